// Round 6
// baseline (388.468 us; speedup 1.0000x reference)
//
#include <hip/hip_runtime.h>
#include <hip/hip_bf16.h>
#include <hip/hip_cooperative_groups.h>
#include <stdint.h>

namespace cg = cooperative_groups;

#define BATCH   16384
#define NCLASS  1000
#define CPAD    1024
#define FDIM    1024
#define MARGINF 5.0f

typedef __attribute__((ext_vector_type(4))) float f32x4;
typedef __attribute__((ext_vector_type(8))) short bf16x8;

__device__ __forceinline__ void gload16(const void* g, void* l) {
    __builtin_amdgcn_global_load_lds(
        (const __attribute__((address_space(1))) void*)g,
        (__attribute__((address_space(3))) void*)l, 16, 0, 0);
}

__device__ __forceinline__ unsigned short f2bf(float f) {
    __hip_bfloat16 h = __float2bfloat16(f);
    return __builtin_bit_cast(unsigned short, h);
}

// ---- one 128x128 output tile of t[r,c] = 0.5*c2[c] - dot(A_r, B_c), K=1024,
//      fused per-row min (exclude col==label / col==row) into pout[row][by].
template <bool CC>
__device__ __forceinline__ void gemm_tile(const unsigned short* __restrict__ A,
                                          const unsigned short* __restrict__ B,
                                          const float* __restrict__ c2,
                                          const int* __restrict__ labels,
                                          float* __restrict__ pout,
                                          float* __restrict__ pos,
                                          int bx, int by, char* sA, char* sB)
{
    constexpr int BM = 128, BK = 64, KTOT = 1024, NCT = 8;
    const int t    = threadIdx.x;
    const int lane = t & 63;
    const int wave = t >> 6;
    const int wrow = wave >> 1, wcol = wave & 1;
    const int lo4  = lane & 15, hi2 = lane >> 4;
    const int rowBase = bx * BM;
    const int colBase = by * BM;

    f32x4 acc[4][4];
    #pragma unroll
    for (int m = 0; m < 4; m++)
        #pragma unroll
        for (int n = 0; n < 4; n++) acc[m][n] = (f32x4){0.f, 0.f, 0.f, 0.f};

    const int g_t = t & 7;           // 16B granule within row
    const int r_t = t >> 3;          // row within 32-row chunk

    const unsigned short* ga[4]; const unsigned short* gb[4];
    char* la[4]; char* lb[4];
    #pragma unroll
    for (int cch = 0; cch < 4; ++cch) {
        const int row = cch * 32 + r_t;
        const int sc  = g_t ^ (row & 7);     // pre-swizzled global granule
        ga[cch] = A + (size_t)(rowBase + row) * KTOT + sc * 8;
        gb[cch] = B + (size_t)(colBase + row) * KTOT + sc * 8;
        la[cch] = sA + (cch * 256 + (t & 192)) * 16;   // wave-uniform base; HW adds lane*16
        lb[cch] = sB + (cch * 256 + (t & 192)) * 16;
    }

    for (int kt = 0; kt < KTOT / BK; ++kt) {
        __syncthreads();
        #pragma unroll
        for (int cch = 0; cch < 4; ++cch) {
            gload16(ga[cch], la[cch]);
            gload16(gb[cch], lb[cch]);
            ga[cch] += BK; gb[cch] += BK;
        }
        __syncthreads();     // vmcnt drained -> LDS valid
        #pragma unroll
        for (int ks = 0; ks < 2; ++ks) {
            bf16x8 af[4], bfr[4];
            #pragma unroll
            for (int m = 0; m < 4; m++) {
                const int r    = wrow * 64 + m * 16 + lo4;
                const int slot = (ks * 4 + hi2) ^ (r & 7);
                af[m] = *(const bf16x8*)(sA + r * 128 + slot * 16);
            }
            #pragma unroll
            for (int n = 0; n < 4; n++) {
                const int r    = wcol * 64 + n * 16 + lo4;
                const int slot = (ks * 4 + hi2) ^ (r & 7);
                bfr[n] = *(const bf16x8*)(sB + r * 128 + slot * 16);
            }
            #pragma unroll
            for (int m = 0; m < 4; m++)
                #pragma unroll
                for (int n = 0; n < 4; n++)
                    acc[m][n] = __builtin_amdgcn_mfma_f32_16x16x32_bf16(af[m], bfr[n], acc[m][n], 0, 0, 0);
        }
    }

    __syncthreads();                    // LDS reads done; sA reused as sPM
    float* sPM = (float*)sA;            // [2][128]

    float bias[4]; int colg[4];
    #pragma unroll
    for (int n = 0; n < 4; n++) {
        const int col = colBase + wcol * 64 + n * 16 + lo4;
        colg[n] = col;
        bias[n] = 0.5f * c2[col];          // c2[col>=1000]=1e30 masks padding
    }
    #pragma unroll
    for (int m = 0; m < 4; m++) {
        #pragma unroll
        for (int j = 0; j < 4; j++) {
            const int rloc  = wrow * 64 + m * 16 + hi2 * 4 + j;
            const int rglob = rowBase + rloc;
            const int lab   = CC ? rglob : labels[rglob];
            float vmin = 1e30f;
            #pragma unroll
            for (int n = 0; n < 4; n++) {
                float tv = acc[m][n][j] + bias[n];
                if (colg[n] == lab) {
                    if (!CC) pos[rglob] = tv;   // unique writer across grid
                    tv = 1e30f;
                }
                vmin = fminf(vmin, tv);
            }
            vmin = fminf(vmin, __shfl_xor(vmin, 1, 64));
            vmin = fminf(vmin, __shfl_xor(vmin, 2, 64));
            vmin = fminf(vmin, __shfl_xor(vmin, 4, 64));
            vmin = fminf(vmin, __shfl_xor(vmin, 8, 64));
            if (lo4 == 0) sPM[wcol * BM + rloc] = vmin;
        }
    }
    __syncthreads();
    if (t < BM) {
        const float v = fminf(sPM[t], sPM[BM + t]);
        pout[(size_t)(rowBase + t) * NCT + by] = v;
    }
    __syncthreads();   // protect sPM until all threads pass (next LDS use after loop-top sync)
}

// ---- single cooperative kernel: prep -> (x-convert || CC-gemm) -> main gemm -> loss ----
__launch_bounds__(256, 4)
__global__ void mega(const float* __restrict__ x, const int* __restrict__ labels,
                     const float* __restrict__ centers,
                     unsigned short* xb, unsigned short* cb,
                     float* c2, float* pmin, float* cpmin, float* pos,
                     float* out)
{
    __shared__ __align__(16) char sA[128 * 64 * 2];   // 16 KB
    __shared__ __align__(16) char sB[128 * 64 * 2];   // 16 KB (total 32768)

    cg::grid_group grid = cg::this_grid();
    const int bid = blockIdx.x;
    const int t   = threadIdx.x;
    const int G   = gridDim.x;

    // ---- phase 1a: centers -> bf16 + c2 (one row per block) ----
    for (int k = bid; k < CPAD; k += G) {
        if (k >= NCLASS) {
            ((ushort4*)(cb + (size_t)k * FDIM))[t] = make_ushort4(0, 0, 0, 0);
            if (t == 0) c2[k] = 1e30f;
        } else {
            float4 v = ((const float4*)(centers + (size_t)k * FDIM))[t];
            ushort4 o;
            o.x = f2bf(v.x); o.y = f2bf(v.y); o.z = f2bf(v.z); o.w = f2bf(v.w);
            ((ushort4*)(cb + (size_t)k * FDIM))[t] = o;
            float ss = v.x * v.x + v.y * v.y + v.z * v.z + v.w * v.w;
            #pragma unroll
            for (int s = 1; s < 64; s <<= 1) ss += __shfl_xor(ss, s, 64);
            float* sred = (float*)sB;
            if ((t & 63) == 0) sred[t >> 6] = ss;
            __syncthreads();
            if (t == 0) c2[k] = sred[0] + sred[1] + sred[2] + sred[3];
            __syncthreads();
        }
    }
    if (bid == 0 && t == 0) atomicExch(out, 0.0f);   // device-scope zero for phase-3 atomics
    grid.sync();

    // ---- phase 1b: x -> bf16 (blocks [0,G-64)) || CC gemm (top 64 blocks) ----
    const int xBlocks = G - 64;
    if (bid < xBlocks) {
        const int n4 = BATCH * FDIM / 4;
        for (int i = bid * 256 + t; i < n4; i += xBlocks * 256) {
            float4 v = ((const float4*)x)[i];
            ushort4 o;
            o.x = f2bf(v.x); o.y = f2bf(v.y); o.z = f2bf(v.z); o.w = f2bf(v.w);
            ((ushort4*)xb)[i] = o;
        }
    } else {
        const int tile = bid - xBlocks;              // 0..63
        gemm_tile<true>(cb, cb, c2, labels, cpmin, nullptr, tile & 7, tile >> 3, sA, sB);
    }
    grid.sync();

    // ---- phase 2: main gemm, 1024 uniform tiles ----
    for (int tile = bid; tile < 1024; tile += G)
        gemm_tile<false>(xb, cb, c2, labels, pmin, pos, tile & 127, tile >> 7, sA, sB);
    grid.sync();

    // ---- phase 3: loss + global sum ----
    if (t < 16) {
        float lsum = 0.f;
        for (int r = bid * 16 + t; r < BATCH; r += G * 16) {
            float neg = 1e30f;
            #pragma unroll
            for (int i = 0; i < 8; i++) neg = fminf(neg, pmin[(size_t)r * 8 + i]);
            const int lab = labels[r];
            float cmin = 1e30f;
            #pragma unroll
            for (int i = 0; i < 8; i++) cmin = fminf(cmin, cpmin[(size_t)lab * 8 + i]);
            const float cen = 0.5f * c2[lab] + cmin;
            lsum += fmaxf(pos[r] + MARGINF - neg, 0.f) + fmaxf(MARGINF + 2.0f - cen, 0.f);
        }
        lsum += __shfl_xor(lsum, 1, 64);
        lsum += __shfl_xor(lsum, 2, 64);
        lsum += __shfl_xor(lsum, 4, 64);
        lsum += __shfl_xor(lsum, 8, 64);
        if (t == 0) atomicAdd(out, lsum * (1.0f / (float)BATCH));
    }
}

// ================= fallback path (if cooperative launch is rejected) =================
__global__ void prep(const float* __restrict__ x, const float* __restrict__ c,
                     unsigned short* __restrict__ xb, unsigned short* __restrict__ cb,
                     float* __restrict__ c2, float* __restrict__ out) {
    const int bid = blockIdx.x;
    const int t   = threadIdx.x;
    if (bid == 0 && t == 0) atomicExch(out, 0.0f);
    if (bid < CPAD) {
        const int k = bid;
        if (k >= NCLASS) {
            ((ushort4*)(cb + (size_t)k * FDIM))[t] = make_ushort4(0, 0, 0, 0);
            if (t == 0) c2[k] = 1e30f;
            return;
        }
        float4 v = ((const float4*)(c + (size_t)k * FDIM))[t];
        ushort4 o;
        o.x = f2bf(v.x); o.y = f2bf(v.y); o.z = f2bf(v.z); o.w = f2bf(v.w);
        ((ushort4*)(cb + (size_t)k * FDIM))[t] = o;
        float ss = v.x * v.x + v.y * v.y + v.z * v.z + v.w * v.w;
        #pragma unroll
        for (int s = 1; s < 64; s <<= 1) ss += __shfl_xor(ss, s, 64);
        __shared__ float sred[4];
        int lane = t & 63, wid = t >> 6;
        if (lane == 0) sred[wid] = ss;
        __syncthreads();
        if (t == 0) c2[k] = sred[0] + sred[1] + sred[2] + sred[3];
    } else {
        int i = (bid - CPAD) * 256 + t;
        const int stride = 2048 * 256;
        #pragma unroll
        for (int it = 0; it < 8; ++it, i += stride) {
            float4 v = ((const float4*)x)[i];
            ushort4 o;
            o.x = f2bf(v.x); o.y = f2bf(v.y); o.z = f2bf(v.z); o.w = f2bf(v.w);
            ((ushort4*)xb)[i] = o;
        }
    }
}

__launch_bounds__(256)
__global__ void gemm_min(const unsigned short* __restrict__ xb,
                         const unsigned short* __restrict__ cb,
                         const float* __restrict__ c2,
                         const int* __restrict__ labels,
                         float* __restrict__ pmin, float* __restrict__ cpmin,
                         float* __restrict__ pos)
{
    __shared__ __align__(16) char sA[128 * 64 * 2];
    __shared__ __align__(16) char sB[128 * 64 * 2];
    const int bid = blockIdx.x;
    if (bid >= 1024) {
        const int tile = bid - 1024;
        gemm_tile<true>(cb, cb, c2, labels, cpmin, nullptr, tile & 7, tile >> 3, sA, sB);
    } else {
        gemm_tile<false>(xb, cb, c2, labels, pmin, pos, bid & 127, bid >> 7, sA, sB);
    }
}

__global__ void loss_k(const float* __restrict__ pmin, const float* __restrict__ pos,
                       const int* __restrict__ labels, const float* __restrict__ cpmin,
                       const float* __restrict__ c2, float* __restrict__ out) {
    const int r = blockIdx.x * 256 + threadIdx.x;
    float neg = 1e30f;
    #pragma unroll
    for (int i = 0; i < 8; i++) neg = fminf(neg, pmin[(size_t)r * 8 + i]);
    const int lab = labels[r];
    float cmin = 1e30f;
    #pragma unroll
    for (int i = 0; i < 8; i++) cmin = fminf(cmin, cpmin[(size_t)lab * 8 + i]);
    const float cen = 0.5f * c2[lab] + cmin;
    float v = fmaxf(pos[r] + MARGINF - neg, 0.f) + fmaxf(MARGINF + 2.0f - cen, 0.f);
    #pragma unroll
    for (int s = 1; s < 64; s <<= 1) v += __shfl_xor(v, s, 64);
    __shared__ float sred[4];
    int lane = threadIdx.x & 63, wid = threadIdx.x >> 6;
    if (lane == 0) sred[wid] = v;
    __syncthreads();
    if (threadIdx.x == 0)
        atomicAdd(out, (sred[0] + sred[1] + sred[2] + sred[3]) * (1.0f / (float)BATCH));
}

extern "C" void kernel_launch(void* const* d_in, const int* in_sizes, int n_in,
                              void* d_out, int out_size, void* d_ws, size_t ws_size,
                              hipStream_t stream) {
    const float* x       = (const float*)d_in[0];
    const int*   labels  = (const int*)d_in[1];
    const float* centers = (const float*)d_in[2];
    float* out = (float*)d_out;

    char* ws = (char*)d_ws;
    size_t off = 0;
    unsigned short* xb = (unsigned short*)(ws + off); off += (size_t)BATCH * FDIM * 2;
    unsigned short* cb = (unsigned short*)(ws + off); off += (size_t)CPAD * FDIM * 2;
    float* c2    = (float*)(ws + off); off += (size_t)CPAD * 4;
    float* pmin  = (float*)(ws + off); off += (size_t)BATCH * 8 * 4;
    float* pos   = (float*)(ws + off); off += (size_t)BATCH * 4;
    float* cpmin = (float*)(ws + off); off += (size_t)CPAD * 8 * 4;

    // __launch_bounds__(256,4) caps VGPR<=128 -> 4 blocks/CU guaranteed
    // (LDS 32KB x 4 = 128KB <= 160KB). G = 4 * 256 CUs = 1024.
    int G = 1024;
    int cus = 0, nb = 0, dev = 0;
    (void)hipGetDevice(&dev);
    if (hipDeviceGetAttribute(&cus, hipDeviceAttributeMultiprocessorCount, dev) == hipSuccess && cus > 0 &&
        hipOccupancyMaxActiveBlocksPerMultiprocessor(&nb, mega, 256, 0) == hipSuccess && nb > 0) {
        G = nb * cus;
        if (G > 1024) G = 1024;
    }

    void* args[] = {(void*)&x, (void*)&labels, (void*)&centers, (void*)&xb, (void*)&cb,
                    (void*)&c2, (void*)&pmin, (void*)&cpmin, (void*)&pos, (void*)&out};
    hipError_t e = hipLaunchCooperativeKernel((void*)mega, dim3(G), dim3(256), args, 0, stream);
    if (e != hipSuccess) {
        // fallback: classic 3-node path
        prep<<<dim3(CPAD + 2048), dim3(256), 0, stream>>>(x, centers, xb, cb, c2, out);
        gemm_min<<<dim3(1024 + 64), dim3(256), 0, stream>>>(xb, cb, c2, labels, pmin, cpmin, pos);
        loss_k<<<dim3(BATCH / 256), dim3(256), 0, stream>>>(pmin, pos, labels, cpmin, c2, out);
    }
}

// Round 7
// 163.600 us; speedup vs baseline: 2.3745x; 2.3745x over previous
//
#include <hip/hip_runtime.h>
#include <hip/hip_bf16.h>
#include <stdint.h>

#define BATCH   16384
#define NCLASS  1000
#define CPAD    1024
#define FDIM    1024
#define MARGINF 5.0f

typedef __attribute__((ext_vector_type(4))) float f32x4;
typedef __attribute__((ext_vector_type(8))) short bf16x8;

#define SB()    __builtin_amdgcn_s_barrier()
#define LGKM0() asm volatile("s_waitcnt lgkmcnt(0)" ::: "memory")
#define VMC4()  asm volatile("s_waitcnt vmcnt(4)" ::: "memory")
#define VMC0()  asm volatile("s_waitcnt vmcnt(0)" ::: "memory")
#define SCH0()  __builtin_amdgcn_sched_barrier(0)

__device__ __forceinline__ void gload16(const void* g, void* l) {
    __builtin_amdgcn_global_load_lds(
        (const __attribute__((address_space(1))) void*)g,
        (__attribute__((address_space(3))) void*)l, 16, 0, 0);
}

__device__ __forceinline__ unsigned short f2bf(float f) {
    __hip_bfloat16 h = __float2bfloat16(f);
    return __builtin_bit_cast(unsigned short, h);
}

// ---- prep: blocks [0,1024): centers fp32->bf16 + c2 (pad rows zero / c2=1e30)
//            blocks [1024,3072): x fp32->bf16.  Also zeroes out[0]. ----
__global__ void prep(const float* __restrict__ x, const float* __restrict__ c,
                     unsigned short* __restrict__ xb, unsigned short* __restrict__ cb,
                     float* __restrict__ c2, float* __restrict__ out) {
    const int bid = blockIdx.x;
    const int t   = threadIdx.x;
    if (bid == 0 && t == 0) atomicExch(out, 0.0f);
    if (bid < CPAD) {
        const int k = bid;
        if (k >= NCLASS) {
            ((ushort4*)(cb + (size_t)k * FDIM))[t] = make_ushort4(0, 0, 0, 0);
            if (t == 0) c2[k] = 1e30f;
            return;
        }
        float4 v = ((const float4*)(c + (size_t)k * FDIM))[t];
        ushort4 o;
        o.x = f2bf(v.x); o.y = f2bf(v.y); o.z = f2bf(v.z); o.w = f2bf(v.w);
        ((ushort4*)(cb + (size_t)k * FDIM))[t] = o;
        float ss = v.x * v.x + v.y * v.y + v.z * v.z + v.w * v.w;
        #pragma unroll
        for (int s = 1; s < 64; s <<= 1) ss += __shfl_xor(ss, s, 64);
        __shared__ float sred[4];
        int lane = t & 63, wid = t >> 6;
        if (lane == 0) sred[wid] = ss;
        __syncthreads();
        if (t == 0) c2[k] = sred[0] + sred[1] + sred[2] + sred[3];
    } else {
        int i = (bid - CPAD) * 256 + t;
        const int stride = 2048 * 256;
        #pragma unroll
        for (int it = 0; it < 8; ++it, i += stride) {
            float4 v = ((const float4*)x)[i];
            ushort4 o;
            o.x = f2bf(v.x); o.y = f2bf(v.y); o.z = f2bf(v.z); o.w = f2bf(v.w);
            ((ushort4*)xb)[i] = o;
        }
    }
}

// ---- CC GEMM: 128x128 tiles over centers x centers (R1/R4-proven 2-phase path) ----
__launch_bounds__(256)
__global__ void cc_gemm(const unsigned short* __restrict__ cb,
                        const float* __restrict__ c2,
                        float* __restrict__ cpmin)          // [1024][8]
{
    __shared__ __align__(16) char sA[128 * 64 * 2];
    __shared__ __align__(16) char sB[128 * 64 * 2];
    const int bid = blockIdx.x;          // 64 blocks
    const int bx = bid & 7, by = bid >> 3;
    const int t    = threadIdx.x;
    const int lane = t & 63;
    const int wave = t >> 6;
    const int wrow = wave >> 1, wcol = wave & 1;
    const int lo4  = lane & 15, hi2 = lane >> 4;
    const int rowBase = bx * 128, colBase = by * 128;

    f32x4 acc[4][4];
    #pragma unroll
    for (int m = 0; m < 4; m++)
        #pragma unroll
        for (int n = 0; n < 4; n++) acc[m][n] = (f32x4){0.f, 0.f, 0.f, 0.f};

    const int g_t = t & 7, r_t = t >> 3;
    const unsigned short* ga[4]; const unsigned short* gb[4];
    char* la[4]; char* lb[4];
    #pragma unroll
    for (int cch = 0; cch < 4; ++cch) {
        const int row = cch * 32 + r_t;
        const int sc  = g_t ^ (row & 7);
        ga[cch] = cb + (size_t)(rowBase + row) * FDIM + sc * 8;
        gb[cch] = cb + (size_t)(colBase + row) * FDIM + sc * 8;
        la[cch] = sA + (cch * 256 + (t & 192)) * 16;
        lb[cch] = sB + (cch * 256 + (t & 192)) * 16;
    }
    for (int kt = 0; kt < 16; ++kt) {
        __syncthreads();
        #pragma unroll
        for (int cch = 0; cch < 4; ++cch) {
            gload16(ga[cch], la[cch]);
            gload16(gb[cch], lb[cch]);
            ga[cch] += 64; gb[cch] += 64;
        }
        __syncthreads();
        #pragma unroll
        for (int ks = 0; ks < 2; ++ks) {
            bf16x8 af[4], bfr[4];
            #pragma unroll
            for (int m = 0; m < 4; m++) {
                const int r = wrow * 64 + m * 16 + lo4;
                const int slot = (ks * 4 + hi2) ^ (r & 7);
                af[m] = *(const bf16x8*)(sA + r * 128 + slot * 16);
            }
            #pragma unroll
            for (int n = 0; n < 4; n++) {
                const int r = wcol * 64 + n * 16 + lo4;
                const int slot = (ks * 4 + hi2) ^ (r & 7);
                bfr[n] = *(const bf16x8*)(sB + r * 128 + slot * 16);
            }
            #pragma unroll
            for (int m = 0; m < 4; m++)
                #pragma unroll
                for (int n = 0; n < 4; n++)
                    acc[m][n] = __builtin_amdgcn_mfma_f32_16x16x32_bf16(af[m], bfr[n], acc[m][n], 0, 0, 0);
        }
    }
    __syncthreads();
    float* sPM = (float*)sA;
    float bias[4]; int colg[4];
    #pragma unroll
    for (int n = 0; n < 4; n++) {
        const int col = colBase + wcol * 64 + n * 16 + lo4;
        colg[n] = col;
        bias[n] = 0.5f * c2[col];
    }
    #pragma unroll
    for (int m = 0; m < 4; m++) {
        #pragma unroll
        for (int j = 0; j < 4; j++) {
            const int rloc  = wrow * 64 + m * 16 + hi2 * 4 + j;
            const int rglob = rowBase + rloc;
            float vmin = 1e30f;
            #pragma unroll
            for (int n = 0; n < 4; n++) {
                float tv = acc[m][n][j] + bias[n];
                if (colg[n] == rglob) tv = 1e30f;
                vmin = fminf(vmin, tv);
            }
            vmin = fminf(vmin, __shfl_xor(vmin, 1, 64));
            vmin = fminf(vmin, __shfl_xor(vmin, 2, 64));
            vmin = fminf(vmin, __shfl_xor(vmin, 4, 64));
            vmin = fminf(vmin, __shfl_xor(vmin, 8, 64));
            if (lo4 == 0) sPM[wcol * 128 + rloc] = vmin;
        }
    }
    __syncthreads();
    if (t < 128)
        cpmin[(size_t)(rowBase + t) * 8 + by] = fminf(sPM[t], sPM[128 + t]);
}

// ---- main GEMM: 256x256 tiles, 8-phase counted-vmcnt pipeline (T3+T4+T5) ----
// Grid 256 blocks x 512 threads, 1 block/CU (LDS 128KB), zero tail.
// LDS per dbuf slot (64KB): A-Kh0 | A-Kh1 | B-Kh0 | B-Kh1, each [256 rows][32 k]
// with per-row granule swizzle g^(row&3) (0-conflict; same involution on
// staging source and ds_read).  vmcnt(4) at P2/P4 ends only — 4 loads always
// in flight; never drained in steady state.
__launch_bounds__(512, 2)
__global__ void gemm8(const unsigned short* __restrict__ xb,   // [16384][1024]
                      const unsigned short* __restrict__ cb,   // [1024][1024]
                      const float* __restrict__ c2,
                      const int* __restrict__ labels,
                      float* __restrict__ pmin,                // [16384][4]
                      float* __restrict__ pos)                 // [16384]
{
    __shared__ __align__(16) char L[131072];

    const int bid = blockIdx.x;
    const int tid = (bid & 7) * 32 + (bid >> 3);    // XCD swizzle (256 = 8*32, bijective)
    const int bx = tid >> 2, by = tid & 3;
    const int rowBase = bx * 256, colBase = by * 256;

    const int t    = threadIdx.x;
    const int lane = t & 63;
    const int w    = t >> 6;                        // 0..7
    const int wrow = w >> 2, wcol = w & 3;          // 2 x 4 wave grid
    const int lo4  = lane & 15, hi2 = lane >> 4;
    const int wb   = w << 10;                       // wave-uniform LDS chunk (w*1024)

    // staging constants: thread stages LDS granules p = l*512 + t (l=0,1)
    const int srow = t >> 2;                        // 0..127
    const int g0   = (t & 3) ^ (srow & 3);          // pre-swizzled source granule
    const unsigned short* sApt[2];
    const unsigned short* sBpt[2];
    sApt[0] = xb + (size_t)(rowBase + srow)       * FDIM + g0 * 8;
    sApt[1] = xb + (size_t)(rowBase + 128 + srow) * FDIM + g0 * 8;
    sBpt[0] = cb + (size_t)(colBase + srow)       * FDIM + g0 * 8;
    sBpt[1] = cb + (size_t)(colBase + 128 + srow) * FDIM + g0 * 8;

    auto stage = [&](int ldsOff, const unsigned short* s0, const unsigned short* s1) {
        gload16(s0, L + ldsOff + wb);
        gload16(s1, L + ldsOff + 8192 + wb);
    };

    const int gsw = ((hi2 ^ (lo4 & 3)) << 4);       // read-side swizzled granule byte
    auto LDA = [&](int slot, int ks, int m) -> bf16x8 {
        const int r = wrow * 128 + m * 16 + lo4;
        return *(const bf16x8*)(L + slot + ks * 16384 + r * 64 + gsw);
    };
    auto LDB = [&](int slot, int ks, int n) -> bf16x8 {
        const int r = wcol * 64 + n * 16 + lo4;
        return *(const bf16x8*)(L + slot + 32768 + ks * 16384 + r * 64 + gsw);
    };

    f32x4 acc[8][4];
    #pragma unroll
    for (int m = 0; m < 8; m++)
        #pragma unroll
        for (int n = 0; n < 4; n++) acc[m][n] = (f32x4){0.f, 0.f, 0.f, 0.f};

    bf16x8 af[8], b0, b1;

#define MFMA16(N0, N1, B0_, B1_)                                                   \
    __builtin_amdgcn_s_setprio(1);                                                 \
    _Pragma("unroll")                                                              \
    for (int m = 0; m < 8; ++m) {                                                  \
        acc[m][N0] = __builtin_amdgcn_mfma_f32_16x16x32_bf16(af[m], B0_, acc[m][N0], 0, 0, 0); \
        acc[m][N1] = __builtin_amdgcn_mfma_f32_16x16x32_bf16(af[m], B1_, acc[m][N1], 0, 0, 0); \
    }                                                                              \
    __builtin_amdgcn_s_setprio(0);

    // ---- prologue: stage tile 0 fully, drain once ----
    stage(0,         sApt[0],      sApt[1]);        // A-Kh0
    stage(32768,     sBpt[0],      sBpt[1]);        // B-Kh0
    stage(16384,     sApt[0] + 32, sApt[1] + 32);   // A-Kh1
    stage(49152,     sBpt[0] + 32, sBpt[1] + 32);   // B-Kh1
    VMC0();
    SB();

    for (int kt = 0; kt < 15; ++kt) {
        const int slot  = (kt & 1) << 16;
        const int nslot = slot ^ 65536;
        const int nk = (kt + 1) * 64;
        // P1: ks0, n0/n1 | stage A-Kh0(kt+1)
        #pragma unroll
        for (int m = 0; m < 8; ++m) af[m] = LDA(slot, 0, m);
        b0 = LDB(slot, 0, 0); b1 = LDB(slot, 0, 1);
        stage(nslot, sApt[0] + nk, sApt[1] + nk);
        SB(); LGKM0(); SCH0();
        MFMA16(0, 1, b0, b1);
        SB();
        // P2: ks0, n2/n3 | stage B-Kh0(kt+1) | vmcnt(4)
        b0 = LDB(slot, 0, 2); b1 = LDB(slot, 0, 3);
        stage(nslot + 32768, sBpt[0] + nk, sBpt[1] + nk);
        SB(); LGKM0(); SCH0();
        MFMA16(2, 3, b0, b1);
        VMC4();
        SB();
        // P3: ks1, n0/n1 | stage A-Kh1(kt+1)
        #pragma unroll
        for (int m = 0; m < 8; ++m) af[m] = LDA(slot, 1, m);
        b0 = LDB(slot, 1, 0); b1 = LDB(slot, 1, 1);
        stage(nslot + 16384, sApt[0] + nk + 32, sApt[1] + nk + 32);
        SB(); LGKM0(); SCH0();
        MFMA16(0, 1, b0, b1);
        SB();
        // P4: ks1, n2/n3 | stage B-Kh1(kt+1) | vmcnt(4)
        b0 = LDB(slot, 1, 2); b1 = LDB(slot, 1, 3);
        stage(nslot + 49152, sBpt[0] + nk + 32, sBpt[1] + nk + 32);
        SB(); LGKM0(); SCH0();
        MFMA16(2, 3, b0, b1);
        VMC4();
        SB();
    }
    // ---- kt = 15 peeled (slot 1, no staging; drain Kh1 loads at P2 end) ----
    {
        const int slot = 65536;
        #pragma unroll
        for (int m = 0; m < 8; ++m) af[m] = LDA(slot, 0, m);
        b0 = LDB(slot, 0, 0); b1 = LDB(slot, 0, 1);
        SB(); LGKM0(); SCH0();
        MFMA16(0, 1, b0, b1);
        SB();
        b0 = LDB(slot, 0, 2); b1 = LDB(slot, 0, 3);
        SB(); LGKM0(); SCH0();
        MFMA16(2, 3, b0, b1);
        VMC0();
        SB();
        #pragma unroll
        for (int m = 0; m < 8; ++m) af[m] = LDA(slot, 1, m);
        b0 = LDB(slot, 1, 0); b1 = LDB(slot, 1, 1);
        SB(); LGKM0(); SCH0();
        MFMA16(0, 1, b0, b1);
        SB();
        b0 = LDB(slot, 1, 2); b1 = LDB(slot, 1, 3);
        SB(); LGKM0(); SCH0();
        MFMA16(2, 3, b0, b1);
        SB();
    }

    // ---- epilogue: bias + exclusion + per-row min over 256 cols ----
    float* sPM  = (float*)L;             // [4][256]
    int*   sLab = (int*)(L + 4096);      // [256]
    if (t < 256) sLab[t] = labels[rowBase + t];
    __syncthreads();

    float bias[4]; int colg[4];
    #pragma unroll
    for (int n = 0; n < 4; n++) {
        const int col = colBase + wcol * 64 + n * 16 + lo4;
        colg[n] = col;
        bias[n] = 0.5f * c2[col];        // c2[col>=1000]=1e30 masks padding
    }
    #pragma unroll
    for (int m = 0; m < 8; m++) {
        #pragma unroll
        for (int j = 0; j < 4; j++) {
            const int rloc  = wrow * 128 + m * 16 + hi2 * 4 + j;
            const int rglob = rowBase + rloc;
            const int lab   = sLab[rloc];
            float vmin = 1e30f;
            #pragma unroll
            for (int n = 0; n < 4; n++) {
                float tv = acc[m][n][j] + bias[n];
                if (colg[n] == lab) {
                    pos[rglob] = tv;     // unique writer across grid
                    tv = 1e30f;
                }
                vmin = fminf(vmin, tv);
            }
            vmin = fminf(vmin, __shfl_xor(vmin, 1, 64));
            vmin = fminf(vmin, __shfl_xor(vmin, 2, 64));
            vmin = fminf(vmin, __shfl_xor(vmin, 4, 64));
            vmin = fminf(vmin, __shfl_xor(vmin, 8, 64));
            if (lo4 == 0) sPM[wcol * 256 + rloc] = vmin;
        }
    }
    __syncthreads();
    if (t < 256) {
        const float v = fminf(fminf(sPM[t], sPM[256 + t]), fminf(sPM[512 + t], sPM[768 + t]));
        pmin[(size_t)(rowBase + t) * 4 + by] = v;
    }
#undef MFMA16
}

// ---- fused: neg-min, cen-min, loss, atomic global sum (out pre-zeroed by prep) ----
__global__ void loss_k(const float* __restrict__ pmin, const float* __restrict__ pos,
                       const int* __restrict__ labels, const float* __restrict__ cpmin,
                       const float* __restrict__ c2, float* __restrict__ out) {
    const int r = blockIdx.x * 256 + threadIdx.x;   // 64 x 256 = 16384
    float neg = 1e30f;
    #pragma unroll
    for (int i = 0; i < 4; i++) neg = fminf(neg, pmin[(size_t)r * 4 + i]);
    const int lab = labels[r];
    float cmin = 1e30f;
    #pragma unroll
    for (int i = 0; i < 8; i++) cmin = fminf(cmin, cpmin[(size_t)lab * 8 + i]);
    const float cen = 0.5f * c2[lab] + cmin;
    float v = fmaxf(pos[r] + MARGINF - neg, 0.f) + fmaxf(MARGINF + 2.0f - cen, 0.f);
    #pragma unroll
    for (int s = 1; s < 64; s <<= 1) v += __shfl_xor(v, s, 64);
    __shared__ float sred[4];
    int lane = threadIdx.x & 63, wid = threadIdx.x >> 6;
    if (lane == 0) sred[wid] = v;
    __syncthreads();
    if (threadIdx.x == 0)
        atomicAdd(out, (sred[0] + sred[1] + sred[2] + sred[3]) * (1.0f / (float)BATCH));
}

extern "C" void kernel_launch(void* const* d_in, const int* in_sizes, int n_in,
                              void* d_out, int out_size, void* d_ws, size_t ws_size,
                              hipStream_t stream) {
    const float* x       = (const float*)d_in[0];
    const int*   labels  = (const int*)d_in[1];
    const float* centers = (const float*)d_in[2];
    float* out = (float*)d_out;

    char* ws = (char*)d_ws;
    size_t off = 0;
    unsigned short* xb = (unsigned short*)(ws + off); off += (size_t)BATCH * FDIM * 2;  // 33.55 MB
    unsigned short* cb = (unsigned short*)(ws + off); off += (size_t)CPAD * FDIM * 2;   //  2.10 MB
    float* c2    = (float*)(ws + off); off += (size_t)CPAD * 4;
    float* pmin  = (float*)(ws + off); off += (size_t)BATCH * 4 * 4;
    float* pos   = (float*)(ws + off); off += (size_t)BATCH * 4;
    float* cpmin = (float*)(ws + off); off += (size_t)CPAD * 8 * 4;

    prep<<<dim3(CPAD + 2048), dim3(256), 0, stream>>>(x, centers, xb, cb, c2, out);
    cc_gemm<<<dim3(64), dim3(256), 0, stream>>>(cb, c2, cpmin);
    gemm8<<<dim3(256), dim3(512), 0, stream>>>(xb, cb, c2, labels, pmin, pos);
    loss_k<<<dim3(BATCH / 256), dim3(256), 0, stream>>>(pmin, pos, labels, cpmin, c2, out);
}

// Round 10
// 162.626 us; speedup vs baseline: 2.3887x; 1.0060x over previous
//
#include <hip/hip_runtime.h>
#include <hip/hip_bf16.h>
#include <stdint.h>

#define BATCH   16384
#define NCLASS  1000
#define CPAD    1024
#define FDIM    1024
#define MARGINF 5.0f

typedef __attribute__((ext_vector_type(4))) float f32x4;
typedef __attribute__((ext_vector_type(8))) short bf16x8;

#define SB()    __builtin_amdgcn_s_barrier()
#define LGKM0() asm volatile("s_waitcnt lgkmcnt(0)" ::: "memory")
#define VMC4()  asm volatile("s_waitcnt vmcnt(4)" ::: "memory")
#define VMC0()  asm volatile("s_waitcnt vmcnt(0)" ::: "memory")
#define SCH0()  __builtin_amdgcn_sched_barrier(0)

__device__ __forceinline__ void gload16(const void* g, void* l) {
    __builtin_amdgcn_global_load_lds(
        (const __attribute__((address_space(1))) void*)g,
        (__attribute__((address_space(3))) void*)l, 16, 0, 0);
}

__device__ __forceinline__ unsigned short f2bf(float f) {
    __hip_bfloat16 h = __float2bfloat16(f);
    return __builtin_bit_cast(unsigned short, h);
}

// ---- prep_c: centers fp32->bf16 + c2 (pad rows zero / c2=1e30); zeroes out[0] ----
__global__ void prep_c(const float* __restrict__ c, unsigned short* __restrict__ cb,
                       float* __restrict__ c2, float* __restrict__ out) {
    const int k = blockIdx.x;     // 0..1023
    const int t = threadIdx.x;
    if (k == 0 && t == 0) atomicExch(out, 0.0f);
    if (k >= NCLASS) {
        ((ushort4*)(cb + (size_t)k * FDIM))[t] = make_ushort4(0, 0, 0, 0);
        if (t == 0) c2[k] = 1e30f;
        return;
    }
    float4 v = ((const float4*)(c + (size_t)k * FDIM))[t];
    ushort4 o;
    o.x = f2bf(v.x); o.y = f2bf(v.y); o.z = f2bf(v.z); o.w = f2bf(v.w);
    ((ushort4*)(cb + (size_t)k * FDIM))[t] = o;
    float ss = v.x * v.x + v.y * v.y + v.z * v.z + v.w * v.w;
    #pragma unroll
    for (int s = 1; s < 64; s <<= 1) ss += __shfl_xor(ss, s, 64);
    __shared__ float sred[4];
    int lane = t & 63, wid = t >> 6;
    if (lane == 0) sred[wid] = ss;
    __syncthreads();
    if (t == 0) c2[k] = sred[0] + sred[1] + sred[2] + sred[3];
}

// ---- CC 128x128 tile (R1-proven 2-phase path), writes cpmin[row][by] ----
__device__ __forceinline__ void cc_tile(const unsigned short* __restrict__ cb,
                                        const float* __restrict__ c2,
                                        float* __restrict__ cpmin,
                                        int bx, int by, char* sA, char* sB)
{
    const int t    = threadIdx.x;
    const int lane = t & 63;
    const int wave = t >> 6;
    const int wrow = wave >> 1, wcol = wave & 1;
    const int lo4  = lane & 15, hi2 = lane >> 4;
    const int rowBase = bx * 128, colBase = by * 128;

    f32x4 acc[4][4];
    #pragma unroll
    for (int m = 0; m < 4; m++)
        #pragma unroll
        for (int n = 0; n < 4; n++) acc[m][n] = (f32x4){0.f, 0.f, 0.f, 0.f};

    const int g_t = t & 7, r_t = t >> 3;
    const unsigned short* ga[4]; const unsigned short* gb[4];
    char* la[4]; char* lb[4];
    #pragma unroll
    for (int cch = 0; cch < 4; ++cch) {
        const int row = cch * 32 + r_t;
        const int sc  = g_t ^ (row & 7);
        ga[cch] = cb + (size_t)(rowBase + row) * FDIM + sc * 8;
        gb[cch] = cb + (size_t)(colBase + row) * FDIM + sc * 8;
        la[cch] = sA + (cch * 256 + (t & 192)) * 16;
        lb[cch] = sB + (cch * 256 + (t & 192)) * 16;
    }
    for (int kt = 0; kt < 16; ++kt) {
        __syncthreads();
        #pragma unroll
        for (int cch = 0; cch < 4; ++cch) {
            gload16(ga[cch], la[cch]);
            gload16(gb[cch], lb[cch]);
            ga[cch] += 64; gb[cch] += 64;
        }
        __syncthreads();
        #pragma unroll
        for (int ks = 0; ks < 2; ++ks) {
            bf16x8 af[4], bfr[4];
            #pragma unroll
            for (int m = 0; m < 4; m++) {
                const int r = wrow * 64 + m * 16 + lo4;
                const int slot = (ks * 4 + hi2) ^ (r & 7);
                af[m] = *(const bf16x8*)(sA + r * 128 + slot * 16);
            }
            #pragma unroll
            for (int n = 0; n < 4; n++) {
                const int r = wcol * 64 + n * 16 + lo4;
                const int slot = (ks * 4 + hi2) ^ (r & 7);
                bfr[n] = *(const bf16x8*)(sB + r * 128 + slot * 16);
            }
            #pragma unroll
            for (int m = 0; m < 4; m++)
                #pragma unroll
                for (int n = 0; n < 4; n++)
                    acc[m][n] = __builtin_amdgcn_mfma_f32_16x16x32_bf16(af[m], bfr[n], acc[m][n], 0, 0, 0);
        }
    }
    __syncthreads();
    float* sPM = (float*)sA;
    float bias[4]; int colg[4];
    #pragma unroll
    for (int n = 0; n < 4; n++) {
        const int col = colBase + wcol * 64 + n * 16 + lo4;
        colg[n] = col;
        bias[n] = 0.5f * c2[col];
    }
    #pragma unroll
    for (int m = 0; m < 4; m++) {
        #pragma unroll
        for (int j = 0; j < 4; j++) {
            const int rloc  = wrow * 64 + m * 16 + hi2 * 4 + j;
            const int rglob = rowBase + rloc;
            float vmin = 1e30f;
            #pragma unroll
            for (int n = 0; n < 4; n++) {
                float tv = acc[m][n][j] + bias[n];
                if (colg[n] == rglob) tv = 1e30f;
                vmin = fminf(vmin, tv);
            }
            vmin = fminf(vmin, __shfl_xor(vmin, 1, 64));
            vmin = fminf(vmin, __shfl_xor(vmin, 2, 64));
            vmin = fminf(vmin, __shfl_xor(vmin, 4, 64));
            vmin = fminf(vmin, __shfl_xor(vmin, 8, 64));
            if (lo4 == 0) sPM[wcol * 128 + rloc] = vmin;
        }
    }
    __syncthreads();
    if (t < 128)
        cpmin[(size_t)(rowBase + t) * 8 + by] = fminf(sPM[t], sPM[128 + t]);
}

// ---- prepx_cc: blocks [0,64): CC gemm (overlaps with...); [64,2112): x fp32->bf16 ----
__global__ void prepx_cc(const float* __restrict__ x, unsigned short* __restrict__ xb,
                         const unsigned short* __restrict__ cb,
                         const float* __restrict__ c2, float* __restrict__ cpmin) {
    __shared__ __align__(16) char sA[128 * 64 * 2];
    __shared__ __align__(16) char sB[128 * 64 * 2];
    const int bid = blockIdx.x;
    if (bid < 64) {
        cc_tile(cb, c2, cpmin, bid & 7, bid >> 3, sA, sB);
    } else {
        // 2048 blocks x 256 threads x 8 float4 == 16384*1024/4 exactly
        int i = (bid - 64) * 256 + threadIdx.x;
        const int stride = 2048 * 256;
        #pragma unroll
        for (int it = 0; it < 8; ++it, i += stride) {
            float4 v = ((const float4*)x)[i];
            ushort4 o;
            o.x = f2bf(v.x); o.y = f2bf(v.y); o.z = f2bf(v.z); o.w = f2bf(v.w);
            ((ushort4*)xb)[i] = o;
        }
    }
}

// ---- main GEMM: 256x256 tiles, 8-phase counted-vmcnt pipeline (T3+T4+T5) ----
// LDS panel = [256 rows][32 k] bf16 (64 B/row). Swizzle involution (both sides):
// granule g ^= (row>>1)&3  -> 16 consecutive rows spread over all 8 bank-slots
// exactly 2x (free).  R7's g^=(row&3) was a 4-way conflict (3.1M counts).
__launch_bounds__(512, 2)
__global__ void gemm8(const unsigned short* __restrict__ xb,   // [16384][1024]
                      const unsigned short* __restrict__ cb,   // [1024][1024]
                      const float* __restrict__ c2,
                      const int* __restrict__ labels,
                      float* __restrict__ pmin,                // [16384][4]
                      float* __restrict__ pos)                 // [16384]
{
    __shared__ __align__(16) char L[131072];

    const int bid = blockIdx.x;
    const int tid = (bid & 7) * 32 + (bid >> 3);    // XCD swizzle (256 = 8*32, bijective)
    const int bx = tid >> 2, by = tid & 3;
    const int rowBase = bx * 256, colBase = by * 256;

    const int t    = threadIdx.x;
    const int lane = t & 63;
    const int w    = t >> 6;                        // 0..7
    const int wrow = w >> 2, wcol = w & 3;          // 2 x 4 wave grid
    const int lo4  = lane & 15, hi2 = lane >> 4;
    const int wb   = w << 10;                       // wave-uniform LDS chunk (w*1024)

    // staging: thread t covers LDS granule t (and 512+t); row = t>>2, gslot = t&3.
    // source granule = gslot ^ ((row>>1)&3)  [involution matches read side]
    const int srow = t >> 2;                        // 0..127
    const int g0   = (t & 3) ^ ((t >> 3) & 3);
    const unsigned short* sApt[2];
    const unsigned short* sBpt[2];
    sApt[0] = xb + (size_t)(rowBase + srow)       * FDIM + g0 * 8;
    sApt[1] = xb + (size_t)(rowBase + 128 + srow) * FDIM + g0 * 8;
    sBpt[0] = cb + (size_t)(colBase + srow)       * FDIM + g0 * 8;
    sBpt[1] = cb + (size_t)(colBase + 128 + srow) * FDIM + g0 * 8;

    auto stage = [&](int ldsOff, const unsigned short* s0, const unsigned short* s1) {
        gload16(s0, L + ldsOff + wb);
        gload16(s1, L + ldsOff + 8192 + wb);
    };

    const int gsw = ((hi2 ^ ((lo4 >> 1) & 3)) << 4);   // read-side swizzled granule byte
    auto LDA = [&](int slot, int ks, int m) -> bf16x8 {
        const int r = wrow * 128 + m * 16 + lo4;
        return *(const bf16x8*)(L + slot + ks * 16384 + r * 64 + gsw);
    };
    auto LDB = [&](int slot, int ks, int n) -> bf16x8 {
        const int r = wcol * 64 + n * 16 + lo4;
        return *(const bf16x8*)(L + slot + 32768 + ks * 16384 + r * 64 + gsw);
    };

    f32x4 acc[8][4];
    #pragma unroll
    for (int m = 0; m < 8; m++)
        #pragma unroll
        for (int n = 0; n < 4; n++) acc[m][n] = (f32x4){0.f, 0.f, 0.f, 0.f};

    bf16x8 af[8], b0, b1;

#define MFMA16(N0, N1, B0_, B1_)                                                   \
    __builtin_amdgcn_s_setprio(1);                                                 \
    _Pragma("unroll")                                                              \
    for (int m = 0; m < 8; ++m) {                                                  \
        acc[m][N0] = __builtin_amdgcn_mfma_f32_16x16x32_bf16(af[m], B0_, acc[m][N0], 0, 0, 0); \
        acc[m][N1] = __builtin_amdgcn_mfma_f32_16x16x32_bf16(af[m], B1_, acc[m][N1], 0, 0, 0); \
    }                                                                              \
    __builtin_amdgcn_s_setprio(0);

    // ---- prologue: stage tile 0 fully, drain once ----
    stage(0,         sApt[0],      sApt[1]);        // A-Kh0
    stage(32768,     sBpt[0],      sBpt[1]);        // B-Kh0
    stage(16384,     sApt[0] + 32, sApt[1] + 32);   // A-Kh1
    stage(49152,     sBpt[0] + 32, sBpt[1] + 32);   // B-Kh1
    VMC0();
    SB();

    for (int kt = 0; kt < 15; ++kt) {
        const int slot  = (kt & 1) << 16;
        const int nslot = slot ^ 65536;
        const int nk = (kt + 1) * 64;
        // P1: ks0, n0/n1 | stage A-Kh0(kt+1)
        #pragma unroll
        for (int m = 0; m < 8; ++m) af[m] = LDA(slot, 0, m);
        b0 = LDB(slot, 0, 0); b1 = LDB(slot, 0, 1);
        stage(nslot, sApt[0] + nk, sApt[1] + nk);
        SB(); LGKM0(); SCH0();
        MFMA16(0, 1, b0, b1);
        SB();
        // P2: ks0, n2/n3 | stage B-Kh0(kt+1) | vmcnt(4)
        b0 = LDB(slot, 0, 2); b1 = LDB(slot, 0, 3);
        stage(nslot + 32768, sBpt[0] + nk, sBpt[1] + nk);
        SB(); LGKM0(); SCH0();
        MFMA16(2, 3, b0, b1);
        VMC4();
        SB();
        // P3: ks1, n0/n1 | stage A-Kh1(kt+1)
        #pragma unroll
        for (int m = 0; m < 8; ++m) af[m] = LDA(slot, 1, m);
        b0 = LDB(slot, 1, 0); b1 = LDB(slot, 1, 1);
        stage(nslot + 16384, sApt[0] + nk + 32, sApt[1] + nk + 32);
        SB(); LGKM0(); SCH0();
        MFMA16(0, 1, b0, b1);
        SB();
        // P4: ks1, n2/n3 | stage B-Kh1(kt+1) | vmcnt(4)
        b0 = LDB(slot, 1, 2); b1 = LDB(slot, 1, 3);
        stage(nslot + 49152, sBpt[0] + nk + 32, sBpt[1] + nk + 32);
        SB(); LGKM0(); SCH0();
        MFMA16(2, 3, b0, b1);
        VMC4();
        SB();
    }
    // ---- kt = 15 peeled (slot 1, no staging) ----
    {
        const int slot = 65536;
        #pragma unroll
        for (int m = 0; m < 8; ++m) af[m] = LDA(slot, 0, m);
        b0 = LDB(slot, 0, 0); b1 = LDB(slot, 0, 1);
        SB(); LGKM0(); SCH0();
        MFMA16(0, 1, b0, b1);
        SB();
        b0 = LDB(slot, 0, 2); b1 = LDB(slot, 0, 3);
        SB(); LGKM0(); SCH0();
        MFMA16(2, 3, b0, b1);
        VMC0();
        SB();
        #pragma unroll
        for (int m = 0; m < 8; ++m) af[m] = LDA(slot, 1, m);
        b0 = LDB(slot, 1, 0); b1 = LDB(slot, 1, 1);
        SB(); LGKM0(); SCH0();
        MFMA16(0, 1, b0, b1);
        SB();
        b0 = LDB(slot, 1, 2); b1 = LDB(slot, 1, 3);
        SB(); LGKM0(); SCH0();
        MFMA16(2, 3, b0, b1);
        SB();
    }

    // ---- epilogue: bias + exclusion + per-row min over 256 cols ----
    float* sPM  = (float*)L;             // [4][256]
    int*   sLab = (int*)(L + 4096);      // [256]
    if (t < 256) sLab[t] = labels[rowBase + t];
    __syncthreads();

    float bias[4]; int colg[4];
    #pragma unroll
    for (int n = 0; n < 4; n++) {
        const int col = colBase + wcol * 64 + n * 16 + lo4;
        colg[n] = col;
        bias[n] = 0.5f * c2[col];        // c2[col>=1000]=1e30 masks padding
    }
    #pragma unroll
    for (int m = 0; m < 8; m++) {
        #pragma unroll
        for (int j = 0; j < 4; j++) {
            const int rloc  = wrow * 128 + m * 16 + hi2 * 4 + j;
            const int rglob = rowBase + rloc;
            const int lab   = sLab[rloc];
            float vmin = 1e30f;
            #pragma unroll
            for (int n = 0; n < 4; n++) {
                float tv = acc[m][n][j] + bias[n];
                if (colg[n] == lab) {
                    pos[rglob] = tv;     // unique writer across grid
                    tv = 1e30f;
                }
                vmin = fminf(vmin, tv);
            }
            vmin = fminf(vmin, __shfl_xor(vmin, 1, 64));
            vmin = fminf(vmin, __shfl_xor(vmin, 2, 64));
            vmin = fminf(vmin, __shfl_xor(vmin, 4, 64));
            vmin = fminf(vmin, __shfl_xor(vmin, 8, 64));
            if (lo4 == 0) sPM[wcol * 256 + rloc] = vmin;
        }
    }
    __syncthreads();
    if (t < 256) {
        const float v = fminf(fminf(sPM[t], sPM[256 + t]), fminf(sPM[512 + t], sPM[768 + t]));
        pmin[(size_t)(rowBase + t) * 4 + by] = v;
    }
#undef MFMA16
}

// ---- fused: neg-min, cen-min, loss, atomic global sum (out pre-zeroed by prep_c) ----
__global__ void loss_k(const float* __restrict__ pmin, const float* __restrict__ pos,
                       const int* __restrict__ labels, const float* __restrict__ cpmin,
                       const float* __restrict__ c2, float* __restrict__ out) {
    const int r = blockIdx.x * 256 + threadIdx.x;   // 64 x 256 = 16384
    float neg = 1e30f;
    #pragma unroll
    for (int i = 0; i < 4; i++) neg = fminf(neg, pmin[(size_t)r * 4 + i]);
    const int lab = labels[r];
    float cmin = 1e30f;
    #pragma unroll
    for (int i = 0; i < 8; i++) cmin = fminf(cmin, cpmin[(size_t)lab * 8 + i]);
    const float cen = 0.5f * c2[lab] + cmin;
    float v = fmaxf(pos[r] + MARGINF - neg, 0.f) + fmaxf(MARGINF + 2.0f - cen, 0.f);
    #pragma unroll
    for (int s = 1; s < 64; s <<= 1) v += __shfl_xor(v, s, 64);
    __shared__ float sred[4];
    int lane = threadIdx.x & 63, wid = threadIdx.x >> 6;
    if (lane == 0) sred[wid] = v;
    __syncthreads();
    if (threadIdx.x == 0)
        atomicAdd(out, (sred[0] + sred[1] + sred[2] + sred[3]) * (1.0f / (float)BATCH));
}

extern "C" void kernel_launch(void* const* d_in, const int* in_sizes, int n_in,
                              void* d_out, int out_size, void* d_ws, size_t ws_size,
                              hipStream_t stream) {
    const float* x       = (const float*)d_in[0];
    const int*   labels  = (const int*)d_in[1];
    const float* centers = (const float*)d_in[2];
    float* out = (float*)d_out;

    char* ws = (char*)d_ws;
    size_t off = 0;
    unsigned short* xb = (unsigned short*)(ws + off); off += (size_t)BATCH * FDIM * 2;  // 33.55 MB
    unsigned short* cb = (unsigned short*)(ws + off); off += (size_t)CPAD * FDIM * 2;   //  2.10 MB
    float* c2    = (float*)(ws + off); off += (size_t)CPAD * 4;
    float* pmin  = (float*)(ws + off); off += (size_t)BATCH * 4 * 4;
    float* pos   = (float*)(ws + off); off += (size_t)BATCH * 4;
    float* cpmin = (float*)(ws + off); off += (size_t)CPAD * 8 * 4;

    prep_c<<<dim3(CPAD), dim3(256), 0, stream>>>(centers, cb, c2, out);
    prepx_cc<<<dim3(64 + 2048), dim3(256), 0, stream>>>(x, xb, cb, c2, cpmin);
    gemm8<<<dim3(256), dim3(512), 0, stream>>>(xb, cb, c2, labels, pmin, pos);
    loss_k<<<dim3(BATCH / 256), dim3(256), 0, stream>>>(pmin, pos, labels, cpmin, c2, out);
}